// Round 1
// baseline (311.797 us; speedup 1.0000x reference)
//
#include <hip/hip_runtime.h>
#include <hip/hip_bf16.h>
#include <cstddef>
#include <cstdint>

#define IN_C 256
#define OUT_C 64
#define NEG_SLOPE 0.2f
#define BKT2 512       // nodes per destination bucket (bucket = c >> 9)
#define PCHUNK 4096    // edges per block in partition kernel
#define MAXB 256       // LDS array size (>= number of buckets = 196)
#define CAP 18432      // fixed record capacity per bucket (mean 16326, +16 sigma)

typedef __attribute__((ext_vector_type(4))) float f32x4;
typedef __attribute__((ext_vector_type(8))) short s16x8;

__device__ __forceinline__ float lrelu_exp(float t)
{
    t = (t >= 0.f) ? t : NEG_SLOPE * t;
    return __expf(t);
}

__device__ __forceinline__ float bf2f(ushort u)
{
    return __uint_as_float(((uint32_t)u) << 16);
}

__device__ __forceinline__ ushort f2bf(float f)
{
    uint32_t u = __float_as_uint(f);
    u += 0x7fffu + ((u >> 16) & 1u);   // round-to-nearest-even
    return (ushort)(u >> 16);
}

// pack two fp32 -> {bf16(f1)<<16 | bf16(f0)}
__device__ __forceinline__ uint32_t pack_bf2(float f0, float f1)
{
    const uint32_t u0 = __float_as_uint(f0) + 0x8000u;
    const uint32_t u1 = __float_as_uint(f1) + 0x8000u;
    return (u1 & 0xffff0000u) | (u0 >> 16);
}

// ---------------------------------------------------------------------------
// W -> bf16 B-fragment order (blocks 0..63); block 64 inits bucket cursors.
// wfrag[((t*4+n)*64 + lane)*8 + j] = W[col][k], k = t*32+(lane>>4)*8+j,
// col = n*16+(lane&15).
// ---------------------------------------------------------------------------
__global__ __launch_bounds__(256) void wconv_kernel(
    const float* __restrict__ W, ushort* __restrict__ wfrag,
    int* __restrict__ cursor, int nb)
{
    if (blockIdx.x == 64) {
        const int i = threadIdx.x;
        if (i < nb) cursor[i] = i * CAP;
        return;
    }
    const int idx = blockIdx.x * 256 + threadIdx.x;
    const int j = idx & 7;
    const int l = (idx >> 3) & 63;
    const int n = (idx >> 9) & 3;
    const int t = idx >> 11;
    const int k   = t * 32 + ((l >> 4) << 3) + j;
    const int col = n * 16 + (l & 15);
    wfrag[idx] = f2bf(W[col * IN_C + k]);
}

// ---------------------------------------------------------------------------
// Kernel 1 (MFMA): h = x @ W^T (bf16 out), s_i = h@a_i, s_j = h@a_j (fp32).
// ---------------------------------------------------------------------------
__global__ __launch_bounds__(256) void fused_h_mfma(
    const float* __restrict__ x, const ushort* __restrict__ wfrag,
    const float* __restrict__ a, ushort* __restrict__ hb,
    float* __restrict__ s_i, float* __restrict__ s_j, int n_nodes)
{
    __shared__ ushort Bs[32 * 64 * 8];   // 32 KB

    const int tid = threadIdx.x;
    for (int i = tid; i < 2048; i += 256)
        ((float4*)Bs)[i] = ((const float4*)wfrag)[i];
    __syncthreads();

    const int lane = tid & 63;
    const int wv   = tid >> 6;
    const int m    = lane & 15;
    const int quad = lane >> 4;

    const int base = blockIdx.x * 64 + wv * 16;
    int row = base + m;
    if (row >= n_nodes) row = n_nodes - 1;   // clamped loads, masked stores

    f32x4 acc0 = {0.f, 0.f, 0.f, 0.f};
    f32x4 acc1 = {0.f, 0.f, 0.f, 0.f};
    f32x4 acc2 = {0.f, 0.f, 0.f, 0.f};
    f32x4 acc3 = {0.f, 0.f, 0.f, 0.f};

    const float* xrow = x + (size_t)row * IN_C + quad * 8;

    #pragma unroll
    for (int t = 0; t < 8; ++t) {
        const float4 xa = *(const float4*)(xrow + t * 32);
        const float4 xb = *(const float4*)(xrow + t * 32 + 4);
        union { s16x8 v; uint32_t u[4]; } af;
        af.u[0] = pack_bf2(xa.x, xa.y);
        af.u[1] = pack_bf2(xa.z, xa.w);
        af.u[2] = pack_bf2(xb.x, xb.y);
        af.u[3] = pack_bf2(xb.z, xb.w);

        const s16x8 b0 = *(const s16x8*)(Bs + ((t * 4 + 0) * 64 + lane) * 8);
        const s16x8 b1 = *(const s16x8*)(Bs + ((t * 4 + 1) * 64 + lane) * 8);
        const s16x8 b2 = *(const s16x8*)(Bs + ((t * 4 + 2) * 64 + lane) * 8);
        const s16x8 b3 = *(const s16x8*)(Bs + ((t * 4 + 3) * 64 + lane) * 8);

        acc0 = __builtin_amdgcn_mfma_f32_16x16x32_bf16(af.v, b0, acc0, 0, 0, 0);
        acc1 = __builtin_amdgcn_mfma_f32_16x16x32_bf16(af.v, b1, acc1, 0, 0, 0);
        acc2 = __builtin_amdgcn_mfma_f32_16x16x32_bf16(af.v, b2, acc2, 0, 0, 0);
        acc3 = __builtin_amdgcn_mfma_f32_16x16x32_bf16(af.v, b3, acc3, 0, 0, 0);
    }

    // epilogue: C/D layout col = lane&15, row = quad*4 + reg
    const int c0 = lane & 15;
    const float ai0 = a[c0],      ai1 = a[c0 + 16], ai2 = a[c0 + 32], ai3 = a[c0 + 48];
    const float aj0 = a[64 + c0], aj1 = a[80 + c0], aj2 = a[96 + c0], aj3 = a[112 + c0];

    #pragma unroll
    for (int r = 0; r < 4; ++r) {
        const int rowr = base + quad * 4 + r;
        float pi = acc0[r] * ai0 + acc1[r] * ai1 + acc2[r] * ai2 + acc3[r] * ai3;
        float pj = acc0[r] * aj0 + acc1[r] * aj1 + acc2[r] * aj2 + acc3[r] * aj3;
        pi += __shfl_xor(pi, 1, 64);  pj += __shfl_xor(pj, 1, 64);
        pi += __shfl_xor(pi, 2, 64);  pj += __shfl_xor(pj, 2, 64);
        pi += __shfl_xor(pi, 4, 64);  pj += __shfl_xor(pj, 4, 64);
        pi += __shfl_xor(pi, 8, 64);  pj += __shfl_xor(pj, 8, 64);
        if (rowr < n_nodes) {
            ushort* hr = hb + (size_t)rowr * OUT_C + c0;
            hr[0]  = f2bf(acc0[r]);
            hr[16] = f2bf(acc1[r]);
            hr[32] = f2bf(acc2[r]);
            hr[48] = f2bf(acc3[r]);
            if (c0 == 0) { s_i[rowr] = pi; s_j[rowr] = pj; }
        }
    }
}

// ---------------------------------------------------------------------------
// Partition into fixed-capacity coarse buckets with LDS reorder.
// Record is now 4 B: r<<9 | (c&511)  (r<2^17, so 26 bits used).
// ex is NOT stored — gather recomputes it from s_i/s_j (bit-identical fp32).
// Register-stage 16 edges/thread, LDS histogram, block scan, one global
// atomicAdd per bucket to reserve, scatter into LDS staging in sorted order,
// then linear coalesced flush.
// ---------------------------------------------------------------------------
__global__ __launch_bounds__(256) void partition_kernel(
    const int* __restrict__ ei, int* __restrict__ cursor,
    uint32_t* __restrict__ rec, int n_edges, int nb)
{
    __shared__ int      hist[MAXB];
    __shared__ int      lbase[MAXB];
    __shared__ int      gbase[MAXB];
    __shared__ int      lcur[MAXB];
    __shared__ uint32_t srt[PCHUNK];    // 16 KB staging
    __shared__ uint8_t  bmap[PCHUNK];   // 4 KB bucket ids

    const int tid  = threadIdx.x;
    const int base = blockIdx.x * PCHUNK;
    const int lim  = min(PCHUNK, n_edges - base);

    hist[tid] = 0;
    __syncthreads();

    int rA[PCHUNK / 256], cA[PCHUNK / 256];
    #pragma unroll
    for (int k = 0; k < PCHUNK / 256; ++k) {
        const int i = tid + (k << 8);
        if (i < lim) {
            rA[k] = ei[base + i];
            cA[k] = ei[n_edges + base + i];
            atomicAdd(&hist[(uint32_t)cA[k] >> 9], 1);
        }
    }
    __syncthreads();

    // block-local exclusive scan of hist + global reserve (one atomic/bucket)
    const int v = hist[tid];
    lbase[tid] = v;
    __syncthreads();
    for (int off = 1; off < 256; off <<= 1) {
        const int mine  = lbase[tid];
        const int other = (tid >= off) ? lbase[tid - off] : 0;
        __syncthreads();
        lbase[tid] = mine + other;
        __syncthreads();
    }
    const int excl = lbase[tid] - v;
    __syncthreads();
    lbase[tid] = excl;
    lcur[tid]  = excl;
    gbase[tid] = (tid < nb && v > 0) ? atomicAdd(&cursor[tid], v) : 0;
    __syncthreads();

    // scatter into LDS staging in block-sorted order
    #pragma unroll
    for (int k = 0; k < PCHUNK / 256; ++k) {
        const int i = tid + (k << 8);
        if (i < lim) {
            const int r = rA[k];
            const int c = cA[k];
            const int b = (uint32_t)c >> 9;
            const int pos = atomicAdd(&lcur[b], 1);
            srt[pos]  = ((uint32_t)r << 9) | (uint32_t)(c & (BKT2 - 1));
            bmap[pos] = (uint8_t)b;
        }
    }
    __syncthreads();

    // linear flush: piecewise-contiguous coalesced burst
    for (int i = tid; i < lim; i += 256) {
        const int b = bmap[i];
        rec[gbase[b] + (i - lbase[b])] = srt[i];
    }
}

// ---------------------------------------------------------------------------
// Refine: one 512-thread block per 512-node bucket (fixed-cap layout).
// 4 B records: stage (72 KB) + histogram + scan, scatter into an LDS
// destination buffer (72 KB) — random stores hit LDS, not L2 — then a
// fully coalesced linear flush to the bucket's global window.
// Emits per-node nodeoff[].  LDS total: 150 KB.
// ---------------------------------------------------------------------------
__global__ __launch_bounds__(512) void refine_kernel(
    uint32_t* __restrict__ rec, const int* __restrict__ cursor,
    int* __restrict__ nodeoff, int n_nodes, int nb)
{
    __shared__ uint32_t recs[CAP];   // 72 KB staging
    __shared__ uint32_t dst[CAP];    // 72 KB sorted destination
    __shared__ int hcnt[BKT2];       // 2 KB
    __shared__ int lcur[BKT2];       // 2 KB
    __shared__ int sscan[BKT2];      // 2 KB

    const int b     = blockIdx.x;
    const int tid   = threadIdx.x;
    const int start = b * CAP;
    const int cnt   = min(cursor[b] - start, CAP);

    hcnt[tid] = 0;
    __syncthreads();

    // stage + histogram
    for (int i = tid; i < cnt; i += 512) {
        const uint32_t rv = rec[start + i];
        recs[i] = rv;
        atomicAdd(&hcnt[rv & (BKT2 - 1)], 1);
    }
    __syncthreads();

    // inclusive scan over 512 node counts
    const int myc = hcnt[tid];
    sscan[tid] = myc;
    __syncthreads();
    for (int off = 1; off < 512; off <<= 1) {
        const int mine  = sscan[tid];
        const int other = (tid >= off) ? sscan[tid - off] : 0;
        __syncthreads();
        sscan[tid] = mine + other;
        __syncthreads();
    }
    const int excl = sscan[tid] - myc;
    lcur[tid] = excl;
    const int g = b * BKT2 + tid;
    if (g < n_nodes) nodeoff[g] = start + excl;
    if (b == nb - 1 && tid == 0) nodeoff[n_nodes] = start + cnt;
    __syncthreads();

    // scatter into per-node CSR order inside LDS (cheap random stores)
    for (int i = tid; i < cnt; i += 512) {
        const uint32_t rv = recs[i];
        const int pos = atomicAdd(&lcur[rv & (BKT2 - 1)], 1);
        dst[pos] = rv;
    }
    __syncthreads();

    // fully coalesced flush of the sorted bucket
    for (int i = tid; i < cnt; i += 512)
        rec[start + i] = dst[i];
}

// ---------------------------------------------------------------------------
// Gather: one wave per destination node, register accumulation, no atomics.
// Unroll 16: sixteen independent 128 B bf16 gathers in flight per wave.
// ex recomputed from s_i (wave scalar) + s_j[r] (broadcast, L2-resident
// 400 KB table) — bit-identical fp32 math to the stored-ex variant.
// Last node of each bucket takes its end from cursor[b] (fixed-cap gaps).
// ---------------------------------------------------------------------------
__global__ __launch_bounds__(256) void gather_kernel(
    const uint32_t* __restrict__ rec, const ushort* __restrict__ hb,
    const float* __restrict__ s_i, const float* __restrict__ s_j,
    const int* __restrict__ nodeoff, const int* __restrict__ cursor,
    float* __restrict__ out, int n_nodes)
{
    int wid = (int)((blockIdx.x * 256u + threadIdx.x) >> 6);
    wid = __builtin_amdgcn_readfirstlane(wid);
    if (wid >= n_nodes) return;
    const int lane = threadIdx.x & 63;

    const int o = nodeoff[wid];
    int oe;
    if ((wid & (BKT2 - 1)) == BKT2 - 1) {
        const int b = wid >> 9;
        oe = min(cursor[b], b * CAP + CAP);   // bucket end (fixed-cap layout)
    } else {
        oe = nodeoff[wid + 1];
    }

    const float si = s_i[wid];

    // self loop: row = col = node
    const float ex0 = lrelu_exp(si + s_j[wid]);
    float acc  = ex0 * bf2f(hb[(size_t)wid * OUT_C + lane]);
    float dsum = ex0;

    int e = o;
    for (; e + 16 <= oe; e += 16) {
        uint32_t rv[16];
        #pragma unroll
        for (int q = 0; q < 16; ++q) rv[q] = rec[e + q];
        float hv[16], sj[16];
        #pragma unroll
        for (int q = 0; q < 16; ++q) {
            const int r = (int)(rv[q] >> 9);
            hv[q] = bf2f(hb[(size_t)r * OUT_C + lane]);
            sj[q] = s_j[r];
        }
        #pragma unroll
        for (int q = 0; q < 16; ++q) {
            const float ex = lrelu_exp(si + sj[q]);
            acc  += ex * hv[q];
            dsum += ex;
        }
    }
    for (; e + 4 <= oe; e += 4) {
        uint32_t rv[4];
        #pragma unroll
        for (int q = 0; q < 4; ++q) rv[q] = rec[e + q];
        float hv[4], sj[4];
        #pragma unroll
        for (int q = 0; q < 4; ++q) {
            const int r = (int)(rv[q] >> 9);
            hv[q] = bf2f(hb[(size_t)r * OUT_C + lane]);
            sj[q] = s_j[r];
        }
        #pragma unroll
        for (int q = 0; q < 4; ++q) {
            const float ex = lrelu_exp(si + sj[q]);
            acc  += ex * hv[q];
            dsum += ex;
        }
    }
    for (; e < oe; ++e) {
        const uint32_t rv = rec[e];
        const int r = (int)(rv >> 9);
        const float ex = lrelu_exp(si + s_j[r]);
        acc  += ex * bf2f(hb[(size_t)r * OUT_C + lane]);
        dsum += ex;
    }

    out[(size_t)wid * OUT_C + lane] = acc / dsum;
}

extern "C" void kernel_launch(void* const* d_in, const int* in_sizes, int n_in,
                              void* d_out, int out_size, void* d_ws, size_t ws_size,
                              hipStream_t stream)
{
    const float* x  = (const float*)d_in[0];
    const int*   ei = (const int*)d_in[1];
    const float* W  = (const float*)d_in[2];
    const float* a  = (const float*)d_in[3];

    const int N  = in_sizes[0] / IN_C;     // 100000
    const int E  = in_sizes[1] / 2;        // 3200000
    const int NB = (N + BKT2 - 1) / BKT2;  // 196

    float* out = (float*)d_out;

    // workspace carve-up (~29 MB)
    char* ws = (char*)d_ws;
    ushort* hb      = (ushort*)ws;                ws += (size_t)N * OUT_C * 2;  // 12.8 MB
    float*  s_i     = (float*)ws;                 ws += (size_t)N * 4;
    float*  s_j     = (float*)ws;                 ws += (size_t)N * 4;
    int*    cursor  = (int*)ws;                   ws += (size_t)MAXB * 4;
    int*    nodeoff = (int*)ws;                   ws += (size_t)(N + 1) * 4;
    ws = (char*)(((uintptr_t)ws + 15) & ~(uintptr_t)15);
    ushort* wfrag   = (ushort*)ws;                ws += 32 * 64 * 8 * 2;        // 32 KB
    ws = (char*)(((uintptr_t)ws + 15) & ~(uintptr_t)15);
    uint32_t* rec   = (uint32_t*)ws;              // NB * CAP * 4 B = 14.5 MB

    // 1. W fragment conversion + cursor init, then projection (MFMA)
    hipLaunchKernelGGL(wconv_kernel, dim3(65), dim3(256), 0, stream,
                       W, wfrag, cursor, NB);
    hipLaunchKernelGGL(fused_h_mfma, dim3((N + 63) / 64), dim3(256), 0, stream,
                       x, wfrag, a, hb, s_i, s_j, N);

    // 2. partition into fixed-capacity coarse buckets (4 B records)
    const int pblocks = (E + PCHUNK - 1) / PCHUNK;
    hipLaunchKernelGGL(partition_kernel, dim3(pblocks), dim3(256), 0, stream,
                       ei, cursor, rec, E, NB);

    // 3. refine buckets into per-node CSR order (LDS scatter + coalesced flush)
    hipLaunchKernelGGL(refine_kernel, dim3(NB), dim3(512), 0, stream,
                       rec, cursor, nodeoff, N, NB);

    // 4. gather-aggregate (one wave per node, register accumulation)
    hipLaunchKernelGGL(gather_kernel, dim3((N + 3) / 4), dim3(256), 0, stream,
                       rec, hb, s_i, s_j, nodeoff, cursor, out, N);
}

// Round 3
// 299.292 us; speedup vs baseline: 1.0418x; 1.0418x over previous
//
#include <hip/hip_runtime.h>
#include <hip/hip_bf16.h>
#include <cstddef>
#include <cstdint>

#define IN_C 256
#define OUT_C 64
#define NEG_SLOPE 0.2f
#define BKT2 512       // nodes per destination bucket (bucket = c >> 9)
#define PCHUNK 4096    // edges per block in partition kernel
#define MAXB 256       // LDS array size (>= number of buckets = 196)
#define CAP 18432      // fixed record capacity per bucket (mean 16326, +16 sigma)

typedef __attribute__((ext_vector_type(4))) float f32x4;
typedef __attribute__((ext_vector_type(8))) short s16x8;

__device__ __forceinline__ float lrelu_exp(float t)
{
    t = (t >= 0.f) ? t : NEG_SLOPE * t;
    return __expf(t);
}

__device__ __forceinline__ float bf2f(ushort u)
{
    return __uint_as_float(((uint32_t)u) << 16);
}

__device__ __forceinline__ ushort f2bf(float f)
{
    uint32_t u = __float_as_uint(f);
    u += 0x7fffu + ((u >> 16) & 1u);   // round-to-nearest-even
    return (ushort)(u >> 16);
}

// pack two fp32 -> {bf16(f1)<<16 | bf16(f0)}
__device__ __forceinline__ uint32_t pack_bf2(float f0, float f1)
{
    const uint32_t u0 = __float_as_uint(f0) + 0x8000u;
    const uint32_t u1 = __float_as_uint(f1) + 0x8000u;
    return (u1 & 0xffff0000u) | (u0 >> 16);
}

// ---------------------------------------------------------------------------
// W -> bf16 B-fragment order (blocks 0..63); block 64 inits bucket cursors.
// ---------------------------------------------------------------------------
__global__ __launch_bounds__(256) void wconv_kernel(
    const float* __restrict__ W, ushort* __restrict__ wfrag,
    int* __restrict__ cursor, int nb)
{
    if (blockIdx.x == 64) {
        const int i = threadIdx.x;
        if (i < nb) cursor[i] = i * CAP;
        return;
    }
    const int idx = blockIdx.x * 256 + threadIdx.x;
    const int j = idx & 7;
    const int l = (idx >> 3) & 63;
    const int n = (idx >> 9) & 3;
    const int t = idx >> 11;
    const int k   = t * 32 + ((l >> 4) << 3) + j;
    const int col = n * 16 + (l & 15);
    wfrag[idx] = f2bf(W[col * IN_C + k]);
}

// ---------------------------------------------------------------------------
// Kernel 1 (MFMA): h = x @ W^T (bf16 out), s_i = h@a_i, s_j = h@a_j (fp32).
// ---------------------------------------------------------------------------
__global__ __launch_bounds__(256) void fused_h_mfma(
    const float* __restrict__ x, const ushort* __restrict__ wfrag,
    const float* __restrict__ a, ushort* __restrict__ hb,
    float* __restrict__ s_i, float* __restrict__ s_j, int n_nodes)
{
    __shared__ ushort Bs[32 * 64 * 8];   // 32 KB

    const int tid = threadIdx.x;
    for (int i = tid; i < 2048; i += 256)
        ((float4*)Bs)[i] = ((const float4*)wfrag)[i];
    __syncthreads();

    const int lane = tid & 63;
    const int wv   = tid >> 6;
    const int m    = lane & 15;
    const int quad = lane >> 4;

    const int base = blockIdx.x * 64 + wv * 16;
    int row = base + m;
    if (row >= n_nodes) row = n_nodes - 1;   // clamped loads, masked stores

    f32x4 acc0 = {0.f, 0.f, 0.f, 0.f};
    f32x4 acc1 = {0.f, 0.f, 0.f, 0.f};
    f32x4 acc2 = {0.f, 0.f, 0.f, 0.f};
    f32x4 acc3 = {0.f, 0.f, 0.f, 0.f};

    const float* xrow = x + (size_t)row * IN_C + quad * 8;

    #pragma unroll
    for (int t = 0; t < 8; ++t) {
        const float4 xa = *(const float4*)(xrow + t * 32);
        const float4 xb = *(const float4*)(xrow + t * 32 + 4);
        union { s16x8 v; uint32_t u[4]; } af;
        af.u[0] = pack_bf2(xa.x, xa.y);
        af.u[1] = pack_bf2(xa.z, xa.w);
        af.u[2] = pack_bf2(xb.x, xb.y);
        af.u[3] = pack_bf2(xb.z, xb.w);

        const s16x8 b0 = *(const s16x8*)(Bs + ((t * 4 + 0) * 64 + lane) * 8);
        const s16x8 b1 = *(const s16x8*)(Bs + ((t * 4 + 1) * 64 + lane) * 8);
        const s16x8 b2 = *(const s16x8*)(Bs + ((t * 4 + 2) * 64 + lane) * 8);
        const s16x8 b3 = *(const s16x8*)(Bs + ((t * 4 + 3) * 64 + lane) * 8);

        acc0 = __builtin_amdgcn_mfma_f32_16x16x32_bf16(af.v, b0, acc0, 0, 0, 0);
        acc1 = __builtin_amdgcn_mfma_f32_16x16x32_bf16(af.v, b1, acc1, 0, 0, 0);
        acc2 = __builtin_amdgcn_mfma_f32_16x16x32_bf16(af.v, b2, acc2, 0, 0, 0);
        acc3 = __builtin_amdgcn_mfma_f32_16x16x32_bf16(af.v, b3, acc3, 0, 0, 0);
    }

    // epilogue: C/D layout col = lane&15, row = quad*4 + reg
    const int c0 = lane & 15;
    const float ai0 = a[c0],      ai1 = a[c0 + 16], ai2 = a[c0 + 32], ai3 = a[c0 + 48];
    const float aj0 = a[64 + c0], aj1 = a[80 + c0], aj2 = a[96 + c0], aj3 = a[112 + c0];

    #pragma unroll
    for (int r = 0; r < 4; ++r) {
        const int rowr = base + quad * 4 + r;
        float pi = acc0[r] * ai0 + acc1[r] * ai1 + acc2[r] * ai2 + acc3[r] * ai3;
        float pj = acc0[r] * aj0 + acc1[r] * aj1 + acc2[r] * aj2 + acc3[r] * aj3;
        pi += __shfl_xor(pi, 1, 64);  pj += __shfl_xor(pj, 1, 64);
        pi += __shfl_xor(pi, 2, 64);  pj += __shfl_xor(pj, 2, 64);
        pi += __shfl_xor(pi, 4, 64);  pj += __shfl_xor(pj, 4, 64);
        pi += __shfl_xor(pi, 8, 64);  pj += __shfl_xor(pj, 8, 64);
        if (rowr < n_nodes) {
            ushort* hr = hb + (size_t)rowr * OUT_C + c0;
            hr[0]  = f2bf(acc0[r]);
            hr[16] = f2bf(acc1[r]);
            hr[32] = f2bf(acc2[r]);
            hr[48] = f2bf(acc3[r]);
            if (c0 == 0) { s_i[rowr] = pi; s_j[rowr] = pj; }
        }
    }
}

// ---------------------------------------------------------------------------
// Partition into fixed-capacity coarse buckets with LDS reorder.
// Record is 4 B: r<<9 | (c&511).  ex recomputed in gather.
// ---------------------------------------------------------------------------
__global__ __launch_bounds__(256) void partition_kernel(
    const int* __restrict__ ei, int* __restrict__ cursor,
    uint32_t* __restrict__ rec, int n_edges, int nb)
{
    __shared__ int      hist[MAXB];
    __shared__ int      lbase[MAXB];
    __shared__ int      gbase[MAXB];
    __shared__ int      lcur[MAXB];
    __shared__ uint32_t srt[PCHUNK];    // 16 KB staging
    __shared__ uint8_t  bmap[PCHUNK];   // 4 KB bucket ids

    const int tid  = threadIdx.x;
    const int base = blockIdx.x * PCHUNK;
    const int lim  = min(PCHUNK, n_edges - base);

    hist[tid] = 0;
    __syncthreads();

    int rA[PCHUNK / 256], cA[PCHUNK / 256];
    #pragma unroll
    for (int k = 0; k < PCHUNK / 256; ++k) {
        const int i = tid + (k << 8);
        if (i < lim) {
            rA[k] = ei[base + i];
            cA[k] = ei[n_edges + base + i];
            atomicAdd(&hist[(uint32_t)cA[k] >> 9], 1);
        }
    }
    __syncthreads();

    // block-local exclusive scan of hist + global reserve (one atomic/bucket)
    const int v = hist[tid];
    lbase[tid] = v;
    __syncthreads();
    for (int off = 1; off < 256; off <<= 1) {
        const int mine  = lbase[tid];
        const int other = (tid >= off) ? lbase[tid - off] : 0;
        __syncthreads();
        lbase[tid] = mine + other;
        __syncthreads();
    }
    const int excl = lbase[tid] - v;
    __syncthreads();
    lbase[tid] = excl;
    lcur[tid]  = excl;
    gbase[tid] = (tid < nb && v > 0) ? atomicAdd(&cursor[tid], v) : 0;
    __syncthreads();

    // scatter into LDS staging in block-sorted order
    #pragma unroll
    for (int k = 0; k < PCHUNK / 256; ++k) {
        const int i = tid + (k << 8);
        if (i < lim) {
            const int r = rA[k];
            const int c = cA[k];
            const int b = (uint32_t)c >> 9;
            const int pos = atomicAdd(&lcur[b], 1);
            srt[pos]  = ((uint32_t)r << 9) | (uint32_t)(c & (BKT2 - 1));
            bmap[pos] = (uint8_t)b;
        }
    }
    __syncthreads();

    // linear flush: piecewise-contiguous coalesced burst
    for (int i = tid; i < lim; i += 256) {
        const int b = bmap[i];
        rec[gbase[b] + (i - lbase[b])] = srt[i];
    }
}

// ---------------------------------------------------------------------------
// Refine: one 1024-thread block per 512-node bucket (fixed-cap layout).
// Stage records in LDS (uint4 vectorized), histogram + scan the 512 node
// slots, then scatter DIRECTLY into the bucket's contiguous global window
// (L2-resident, write-merged) — no dst buffer, no flush phase.
// WAR-safe: all stage reads complete before the scan barrier.
// ---------------------------------------------------------------------------
__global__ __launch_bounds__(1024) void refine_kernel(
    uint32_t* __restrict__ rec, const int* __restrict__ cursor,
    int* __restrict__ nodeoff, int n_nodes, int nb)
{
    __shared__ uint32_t recs[CAP];   // 72 KB staging
    __shared__ int hcnt[BKT2];       // 2 KB
    __shared__ int lcur[BKT2];       // 2 KB
    __shared__ int sscan[BKT2];      // 2 KB

    const int b     = blockIdx.x;
    const int tid   = threadIdx.x;
    const int start = b * CAP;
    const int cnt   = min(cursor[b] - start, CAP);

    if (tid < BKT2) hcnt[tid] = 0;
    __syncthreads();

    // stage + histogram (vectorized main body)
    const int cnt4 = cnt >> 2;
    for (int i = tid; i < cnt4; i += 1024) {
        const uint4 rv4 = ((const uint4*)(rec + start))[i];
        ((uint4*)recs)[i] = rv4;
        atomicAdd(&hcnt[rv4.x & (BKT2 - 1)], 1);
        atomicAdd(&hcnt[rv4.y & (BKT2 - 1)], 1);
        atomicAdd(&hcnt[rv4.z & (BKT2 - 1)], 1);
        atomicAdd(&hcnt[rv4.w & (BKT2 - 1)], 1);
    }
    for (int i = (cnt & ~3) + tid; i < cnt; i += 1024) {
        const uint32_t rv = rec[start + i];
        recs[i] = rv;
        atomicAdd(&hcnt[rv & (BKT2 - 1)], 1);
    }
    __syncthreads();

    // inclusive scan over 512 node counts (first 512 threads active)
    if (tid < BKT2) sscan[tid] = hcnt[tid];
    __syncthreads();
    for (int off = 1; off < BKT2; off <<= 1) {
        int mine = 0, other = 0;
        if (tid < BKT2) {
            mine  = sscan[tid];
            other = (tid >= off) ? sscan[tid - off] : 0;
        }
        __syncthreads();
        if (tid < BKT2) sscan[tid] = mine + other;
        __syncthreads();
    }
    if (tid < BKT2) {
        const int myc  = hcnt[tid];
        const int excl = sscan[tid] - myc;
        lcur[tid] = excl;
        const int g = b * BKT2 + tid;
        if (g < n_nodes) nodeoff[g] = start + excl;
    }
    if (b == nb - 1 && tid == 0) nodeoff[n_nodes] = start + cnt;
    __syncthreads();

    // scatter straight into the global bucket window (L2-resident)
    for (int i = tid; i < cnt; i += 1024) {
        const uint32_t rv = recs[i];
        const int pos = atomicAdd(&lcur[rv & (BKT2 - 1)], 1);
        rec[start + pos] = rv;
    }
}

// ---------------------------------------------------------------------------
// Gather: one wave per destination node, 4 edges processed in parallel by
// 4 lane-groups of 16.  Each lane loads 8 B (4 bf16 channels) of its
// group's source row; the lrelu/exp chain covers 4 edges per issue.
// Cross-group shfl_xor(16/32) reduce, one predicated 256 B store per node.
// ex recomputed from s_i (wave scalar) + s_j[r] — same fp32 math as before.
// ---------------------------------------------------------------------------
__global__ __launch_bounds__(256) void gather_kernel(
    const uint32_t* __restrict__ rec, const ushort* __restrict__ hb,
    const float* __restrict__ s_i, const float* __restrict__ s_j,
    const int* __restrict__ nodeoff, const int* __restrict__ cursor,
    float* __restrict__ out, int n_nodes)
{
    int wid = (int)((blockIdx.x * 256u + threadIdx.x) >> 6);
    wid = __builtin_amdgcn_readfirstlane(wid);
    if (wid >= n_nodes) return;
    const int lane = threadIdx.x & 63;
    const int g    = lane >> 4;          // edge slot 0..3
    const int l4   = lane & 15;          // channel group: channels 4*l4..4*l4+3
    const uint32_t loff = (uint32_t)(l4 << 3);   // byte offset within row

    const int o = nodeoff[wid];
    int oe;
    if ((wid & (BKT2 - 1)) == BKT2 - 1) {
        const int b = wid >> 9;
        oe = min(cursor[b], b * CAP + CAP);   // bucket end (fixed-cap layout)
    } else {
        oe = nodeoff[wid + 1];
    }

    const float si = s_i[wid];
    const char* hbB = (const char*)hb;

    f32x4 acc = {0.f, 0.f, 0.f, 0.f};
    float dsum = 0.f;

    int e = o;
    for (; e + 16 <= oe; e += 16) {
        uint32_t rv[4];
        #pragma unroll
        for (int q = 0; q < 4; ++q) rv[q] = rec[e + q * 4 + g];
        float sj[4]; uint32_t off[4];
        #pragma unroll
        for (int q = 0; q < 4; ++q) {
            sj[q]  = s_j[rv[q] >> 9];
            off[q] = ((rv[q] & 0xFFFFFE00u) >> 2) + loff;   // r*128 + l4*8
        }
        uint2 hv[4];
        #pragma unroll
        for (int q = 0; q < 4; ++q) hv[q] = *(const uint2*)(hbB + off[q]);
        #pragma unroll
        for (int q = 0; q < 4; ++q) {
            const float ex = lrelu_exp(si + sj[q]);
            acc[0] += ex * __uint_as_float(hv[q].x << 16);
            acc[1] += ex * __uint_as_float(hv[q].x & 0xffff0000u);
            acc[2] += ex * __uint_as_float(hv[q].y << 16);
            acc[3] += ex * __uint_as_float(hv[q].y & 0xffff0000u);
            dsum += ex;
        }
    }
    for (; e + 4 <= oe; e += 4) {
        const uint32_t rv = rec[e + g];
        const float sj = s_j[rv >> 9];
        const uint32_t off = ((rv & 0xFFFFFE00u) >> 2) + loff;
        const uint2 hv = *(const uint2*)(hbB + off);
        const float ex = lrelu_exp(si + sj);
        acc[0] += ex * __uint_as_float(hv.x << 16);
        acc[1] += ex * __uint_as_float(hv.x & 0xffff0000u);
        acc[2] += ex * __uint_as_float(hv.y << 16);
        acc[3] += ex * __uint_as_float(hv.y & 0xffff0000u);
        dsum += ex;
    }
    if (e < oe) {
        const int m = oe - e;                         // 1..3
        const uint32_t rv = rec[e + (g < m ? g : m - 1)];
        const float sj = s_j[rv >> 9];
        const uint32_t off = ((rv & 0xFFFFFE00u) >> 2) + loff;
        const uint2 hv = *(const uint2*)(hbB + off);
        const float ex = (g < m) ? lrelu_exp(si + sj) : 0.f;
        acc[0] += ex * __uint_as_float(hv.x << 16);
        acc[1] += ex * __uint_as_float(hv.x & 0xffff0000u);
        acc[2] += ex * __uint_as_float(hv.y << 16);
        acc[3] += ex * __uint_as_float(hv.y & 0xffff0000u);
        dsum += ex;
    }

    // cross-group reduction (4 groups of 16 lanes)
    #pragma unroll
    for (int k = 0; k < 4; ++k) {
        acc[k] += __shfl_xor(acc[k], 16, 64);
        acc[k] += __shfl_xor(acc[k], 32, 64);
    }
    dsum += __shfl_xor(dsum, 16, 64);
    dsum += __shfl_xor(dsum, 32, 64);

    // self loop: row = col = node
    const float ex0 = lrelu_exp(si + s_j[wid]);
    const uint2 hs = *(const uint2*)(hbB + (size_t)wid * 128 + loff);
    acc[0] += ex0 * __uint_as_float(hs.x << 16);
    acc[1] += ex0 * __uint_as_float(hs.x & 0xffff0000u);
    acc[2] += ex0 * __uint_as_float(hs.y << 16);
    acc[3] += ex0 * __uint_as_float(hs.y & 0xffff0000u);
    dsum += ex0;

    if (g == 0) {
        float4 o4;
        o4.x = acc[0] / dsum;
        o4.y = acc[1] / dsum;
        o4.z = acc[2] / dsum;
        o4.w = acc[3] / dsum;
        *(float4*)(out + (size_t)wid * OUT_C + (l4 << 2)) = o4;
    }
}

extern "C" void kernel_launch(void* const* d_in, const int* in_sizes, int n_in,
                              void* d_out, int out_size, void* d_ws, size_t ws_size,
                              hipStream_t stream)
{
    const float* x  = (const float*)d_in[0];
    const int*   ei = (const int*)d_in[1];
    const float* W  = (const float*)d_in[2];
    const float* a  = (const float*)d_in[3];

    const int N  = in_sizes[0] / IN_C;     // 100000
    const int E  = in_sizes[1] / 2;        // 3200000
    const int NB = (N + BKT2 - 1) / BKT2;  // 196

    float* out = (float*)d_out;

    // workspace carve-up (~29 MB)
    char* ws = (char*)d_ws;
    ushort* hb      = (ushort*)ws;                ws += (size_t)N * OUT_C * 2;  // 12.8 MB
    float*  s_i     = (float*)ws;                 ws += (size_t)N * 4;
    float*  s_j     = (float*)ws;                 ws += (size_t)N * 4;
    int*    cursor  = (int*)ws;                   ws += (size_t)MAXB * 4;
    int*    nodeoff = (int*)ws;                   ws += (size_t)(N + 1) * 4;
    ws = (char*)(((uintptr_t)ws + 15) & ~(uintptr_t)15);
    ushort* wfrag   = (ushort*)ws;                ws += 32 * 64 * 8 * 2;        // 32 KB
    ws = (char*)(((uintptr_t)ws + 15) & ~(uintptr_t)15);
    uint32_t* rec   = (uint32_t*)ws;              // NB * CAP * 4 B = 14.5 MB

    // 1. W fragment conversion + cursor init, then projection (MFMA)
    hipLaunchKernelGGL(wconv_kernel, dim3(65), dim3(256), 0, stream,
                       W, wfrag, cursor, NB);
    hipLaunchKernelGGL(fused_h_mfma, dim3((N + 63) / 64), dim3(256), 0, stream,
                       x, wfrag, a, hb, s_i, s_j, N);

    // 2. partition into fixed-capacity coarse buckets (4 B records)
    const int pblocks = (E + PCHUNK - 1) / PCHUNK;
    hipLaunchKernelGGL(partition_kernel, dim3(pblocks), dim3(256), 0, stream,
                       ei, cursor, rec, E, NB);

    // 3. refine buckets into per-node CSR order (direct L2-window scatter)
    hipLaunchKernelGGL(refine_kernel, dim3(NB), dim3(1024), 0, stream,
                       rec, cursor, nodeoff, N, NB);

    // 4. gather-aggregate (one wave per node, 4 parallel edge slots)
    hipLaunchKernelGGL(gather_kernel, dim3((N + 3) / 4), dim3(256), 0, stream,
                       rec, hb, s_i, s_j, nodeoff, cursor, out, N);
}